// Round 10
// baseline (104.407 us; speedup 1.0000x reference)
//
#include <hip/hip_runtime.h>
#include <hip/hip_bf16.h>
#include <stdint.h>

// SelfBallPointQuery: B=16, C=3, N=2048, RADIUS^2=0.04, MAX_SAMPLES=64.
// R10: transposed bitset. R7-R9 post-mortem: VALU time pinned at ~29us because
// the ballot/mbcnt/cndmask emit machinery (~34 VALU) was paid per 64 TESTED
// pairs (67M). Here lane=query: each wave tests 64 queries against a 256-pt
// j-window at ~11 VALU / 64 pairs, accumulating per-lane bitmasks
// (m = 2m + pred, k descending => bit k = point jbase+k). Emission is sparse
// (~1.3M hits): per-lane ctz loops, slots from an LDS prefix over the 8
// per-wave counts. Order = waves asc x words asc x ffbl asc = ascending j.

#define B_DIM 16
#define N_PTS 2048
#define K_OUT 64
#define R2 0.04f
#define WAVES 8
#define BLOCK_T (WAVES * 64)            // 512
#define JPW (N_PTS / WAVES)             // 256 points per wave
#define WPW (JPW / 32)                  // 8 mask words per lane

__global__ __launch_bounds__(BLOCK_T, 4) void ball_query_kernel(
    const float* __restrict__ pcs,   // (B, 3, N)
    int* __restrict__ out)           // (B, N, 64) int32
{
    __shared__ float xs4[N_PTS * 4]; // float4-padded xyz_, 32 KB
    __shared__ int   cntS[WAVES][64];
    __shared__ int   qfS[WAVES][64];

    const int b    = blockIdx.x >> 5;        // / 32
    const int qg   = blockIdx.x & 31;        // query group (64 queries)
    const int tid  = threadIdx.x;
    const int wave = tid >> 6;
    const int lane = tid & 63;

    // Stage cloud b as float4 per point
    const float* src = pcs + (size_t)b * 3 * N_PTS;
    for (int j = tid; j < N_PTS; j += BLOCK_T) {
        float4 p;
        p.x = src[0 * N_PTS + j];
        p.y = src[1 * N_PTS + j];
        p.z = src[2 * N_PTS + j];
        p.w = 0.0f;
        *(float4*)&xs4[j * 4] = p;
    }
    __syncthreads();

    // my query = lane-th query of this group
    const int qi = qg * 64 + lane;           // in [0, 2048)
    const float qx = xs4[qi * 4 + 0];
    const float qy = xs4[qi * 4 + 1];
    const float qz = xs4[qi * 4 + 2];

    const int jbase = wave * JPW;

    // ---- dense test phase: 8 words x 32 bits per lane ----
    unsigned mask[WPW];
    for (int t = 0; t < WPW; ++t) {
        unsigned m = 0;
        #pragma unroll
        for (int k = 31; k >= 0; --k) {       // descending: bit k = point +k
            const int j = jbase + t * 32 + k;
            const float4 p = *(const float4*)&xs4[j * 4];  // wave-uniform bcast
            const float dx = p.x - qx;
            const float dy = p.y - qy;
            const float dz = p.z - qz;
            // exact numpy f32 association, no FMA contraction:
            const float d2 = __fadd_rn(__fadd_rn(__fmul_rn(dx, dx),
                                                 __fmul_rn(dy, dy)),
                                       __fmul_rn(dz, dz));
            m = m + m + (unsigned)(d2 < R2);
        }
        mask[t] = m;
    }

    // per-lane count + first hit within this wave's window
    int cnt = 0;
    #pragma unroll
    for (int t = 0; t < WPW; ++t) cnt += __builtin_popcount(mask[t]);
    int qf = -1;
    #pragma unroll
    for (int t = 0; t < WPW; ++t) {
        if (qf < 0 && mask[t] != 0u)
            qf = jbase + t * 32 + __builtin_ctz(mask[t]);
    }
    cntS[wave][lane] = cnt;
    qfS[wave][lane]  = qf;
    __syncthreads();

    // prefix over earlier waves' counts for my lane's query; global first hit
    int base = 0, tc = 0, gfirst = 0;
    #pragma unroll
    for (int w = 0; w < WAVES; ++w) {
        const int c = cntS[w][lane];
        const int f = qfS[w][lane];
        if (w < wave) base += c;
        gfirst = (tc == 0 && c > 0) ? f : gfirst;
        tc += c;
    }

    int* const orow = out + ((size_t)(b * N_PTS + qi)) * K_OUT;

    // ---- sparse emit: my window's hits land in slots [base, ...) ----
    int slot = base;
    #pragma unroll
    for (int t = 0; t < WPW; ++t) {
        unsigned m = mask[t];
        while (m != 0u && slot < K_OUT) {
            const int k = (int)__builtin_ctz(m);
            orow[slot] = jbase + t * 32 + k;
            m &= m - 1u;
            ++slot;
        }
    }

    // ---- pad: 8 slots per wave cover [0,64); write gfirst where s >= tc ----
    #pragma unroll
    for (int s0 = 0; s0 < K_OUT / WAVES; ++s0) {
        const int s = wave * (K_OUT / WAVES) + s0;
        if (s >= tc) orow[s] = gfirst;
    }
}

extern "C" void kernel_launch(void* const* d_in, const int* in_sizes, int n_in,
                              void* d_out, int out_size, void* d_ws, size_t ws_size,
                              hipStream_t stream) {
    const float* pcs = (const float*)d_in[0];
    int* out = (int*)d_out;
    const int grid = B_DIM * 32;     // 512 blocks (16 batches x 32 query groups)
    ball_query_kernel<<<grid, BLOCK_T, 0, stream>>>(pcs, out);
}